// Round 1
// baseline (735.682 us; speedup 1.0000x reference)
//
#include <hip/hip_runtime.h>
#include <hip/hip_bf16.h>

#define D 128  // D_IN == D_OUT == 128

// ---------------- init: deg = 1.0 (self-loop), cnt = 0 ----------------
__global__ void init_bufs(float* __restrict__ deg, int* __restrict__ cnt, int N) {
    int i = blockIdx.x * 256 + threadIdx.x;
    if (i < N) { deg[i] = 1.0f; cnt[i] = 0; }
}

// ---------------- count pass: deg[col] += ew, cnt[col]++ ----------------
__global__ void count_deg(const int* __restrict__ col, const float* __restrict__ ew,
                          float* __restrict__ deg, int* __restrict__ cnt, int E) {
    int e = blockIdx.x * 256 + threadIdx.x;
    if (e >= E) return;
    int c = col[e];
    atomicAdd(&deg[c], ew[e]);
    atomicAdd(&cnt[c], 1);
}

// ---------------- dinv = rsqrt(deg) in place ----------------
__global__ void compute_dinv(float* __restrict__ deg, int N) {
    int i = blockIdx.x * 256 + threadIdx.x;
    if (i < N) { float d = deg[i]; deg[i] = (d > 0.f) ? rsqrtf(d) : 0.f; }
}

// ---------------- scan kernel 1: per-chunk (1024) sums ----------------
__global__ void scan_blocksum(const int* __restrict__ cnt, int* __restrict__ blocksum, int N) {
    __shared__ int sd[256];
    int tid = threadIdx.x;
    int base = blockIdx.x * 1024 + tid * 4;
    int s = 0;
    #pragma unroll
    for (int j = 0; j < 4; ++j) { int i = base + j; if (i < N) s += cnt[i]; }
    sd[tid] = s; __syncthreads();
    for (int off = 128; off > 0; off >>= 1) {
        if (tid < off) sd[tid] += sd[tid + off];
        __syncthreads();
    }
    if (tid == 0) blocksum[blockIdx.x] = sd[0];
}

// ---------------- scan kernel 2: serial exclusive scan of ~98 block sums ----------------
__global__ void scan_serial(int* __restrict__ blocksum, int nb) {
    if (threadIdx.x == 0 && blockIdx.x == 0) {
        int run = 0;
        for (int b = 0; b < nb; ++b) { int t = blocksum[b]; blocksum[b] = run; run += t; }
    }
}

// ---------------- scan kernel 3: intra-chunk exclusive scan -> rowptr, cursor ----------------
__global__ void scan_final(const int* __restrict__ cnt, const int* __restrict__ blocksum,
                           int* __restrict__ rowptr, int* __restrict__ cursor, int N) {
    __shared__ int sd[256];
    int tid = threadIdx.x;
    int base = blockIdx.x * 1024 + tid * 4;
    int v[4]; int tsum = 0;
    #pragma unroll
    for (int j = 0; j < 4; ++j) { int i = base + j; v[j] = (i < N) ? cnt[i] : 0; tsum += v[j]; }
    sd[tid] = tsum; __syncthreads();
    // Hillis-Steele inclusive scan over 256 thread sums
    for (int off = 1; off < 256; off <<= 1) {
        int t = (tid >= off) ? sd[tid - off] : 0;
        __syncthreads();
        sd[tid] += t;
        __syncthreads();
    }
    int excl = sd[tid] - tsum + blocksum[blockIdx.x];
    #pragma unroll
    for (int j = 0; j < 4; ++j) {
        int i = base + j;
        if (i < N) { rowptr[i] = excl; cursor[i] = excl; }
        excl += v[j];
    }
}

// ---------------- scatter edges into CSR-by-target order ----------------
__global__ void scatter_edges(const int* __restrict__ rowi, const int* __restrict__ coli,
                              const float* __restrict__ ew, const float* __restrict__ dinv,
                              int* __restrict__ cursor, int2* __restrict__ sorted, int E) {
    int e = blockIdx.x * 256 + threadIdx.x;
    if (e >= E) return;
    int r = rowi[e], c = coli[e];
    float w = dinv[r] * ew[e];   // fold dinv[row]*ew into per-edge weight
    int pos = atomicAdd(&cursor[c], 1);
    sorted[pos] = make_int2(r, __float_as_int(w));
}

// ---------------- xw = x @ W (fp32 vector GEMM) ----------------
// block = 256 threads: col = tid&127, row-half = tid>>7; each thread does 8 rows.
__global__ __launch_bounds__(256) void gemm_xw(const float* __restrict__ x,
                                               const float* __restrict__ W,
                                               float* __restrict__ xw, int N) {
    int c  = threadIdx.x & 127;
    int rh = threadIdx.x >> 7;
    int row0 = blockIdx.x * 16 + rh * 8;
    if (row0 >= N) return;
    int rows = N - row0; if (rows > 8) rows = 8;
    float acc[8] = {0.f,0.f,0.f,0.f,0.f,0.f,0.f,0.f};
    const float* xp = x + (size_t)row0 * D;
    if (rows == 8) {
        for (int k = 0; k < D; k += 4) {
            float w0 = W[(k+0)*D + c];
            float w1 = W[(k+1)*D + c];
            float w2 = W[(k+2)*D + c];
            float w3 = W[(k+3)*D + c];
            #pragma unroll
            for (int i = 0; i < 8; ++i) {
                float4 xv = *(const float4*)(xp + (size_t)i*D + k);
                acc[i] = fmaf(xv.x, w0, fmaf(xv.y, w1, fmaf(xv.z, w2, fmaf(xv.w, w3, acc[i]))));
            }
        }
        #pragma unroll
        for (int i = 0; i < 8; ++i) xw[(size_t)(row0+i)*D + c] = acc[i];
    } else {
        for (int k = 0; k < D; k += 4) {
            float w0 = W[(k+0)*D + c];
            float w1 = W[(k+1)*D + c];
            float w2 = W[(k+2)*D + c];
            float w3 = W[(k+3)*D + c];
            for (int i = 0; i < rows; ++i) {
                float4 xv = *(const float4*)(xp + (size_t)i*D + k);
                acc[i] = fmaf(xv.x, w0, fmaf(xv.y, w1, fmaf(xv.z, w2, fmaf(xv.w, w3, acc[i]))));
            }
        }
        for (int i = 0; i < rows; ++i) xw[(size_t)(row0+i)*D + c] = acc[i];
    }
}

// ---------------- aggregation: one wave per node, float2 per lane ----------------
__global__ __launch_bounds__(256) void aggregate(const float* __restrict__ xw,
                                                 const float* __restrict__ dinv,
                                                 const int* __restrict__ rowptr,
                                                 const int* __restrict__ cnt,
                                                 const int2* __restrict__ sorted,
                                                 const float* __restrict__ bias,
                                                 const float* __restrict__ prelu_a,
                                                 float* __restrict__ out, int N) {
    int wid  = threadIdx.x >> 6;
    int lane = threadIdx.x & 63;
    int n = blockIdx.x * 4 + wid;
    if (n >= N) return;
    int d0 = lane * 2;
    float di = dinv[n];
    // self-loop term: norm_self = di*di; factor one di out of everything
    float2 xs = *(const float2*)(xw + (size_t)n * D + d0);
    float ax = di * xs.x;
    float ay = di * xs.y;
    int s = rowptr[n];
    int e = s + cnt[n];
    for (int i = s; i < e; ++i) {
        int2 se = sorted[i];                       // wave-uniform 8B broadcast
        float w = __int_as_float(se.y);            // = dinv[row]*ew
        float2 v = *(const float2*)(xw + (size_t)se.x * D + d0);
        ax = fmaf(w, v.x, ax);
        ay = fmaf(w, v.y, ay);
    }
    float a = prelu_a[0];
    float2 bv = *(const float2*)(bias + d0);
    float ox = fmaf(di, ax, bv.x);
    float oy = fmaf(di, ay, bv.y);
    ox = (ox >= 0.f) ? ox : a * ox;
    oy = (oy >= 0.f) ? oy : a * oy;
    *(float2*)(out + (size_t)n * D + d0) = make_float2(ox, oy);
}

extern "C" void kernel_launch(void* const* d_in, const int* in_sizes, int n_in,
                              void* d_out, int out_size, void* d_ws, size_t ws_size,
                              hipStream_t stream) {
    const float* x       = (const float*)d_in[0];
    const int*   ei      = (const int*)d_in[1];   // [2, E] int32
    const float* ew      = (const float*)d_in[2];
    const float* W       = (const float*)d_in[3];
    const float* bias    = (const float*)d_in[4];
    const float* prelu_a = (const float*)d_in[5];
    float* out = (float*)d_out;

    int N = in_sizes[0] / D;
    int E = in_sizes[2];
    const int* rowi = ei;       // source
    const int* coli = ei + E;   // target

    // workspace layout
    char* ws = (char*)d_ws;
    size_t o = 0;
    float* xw     = (float*)(ws + o); o += (size_t)N * D * 4;   // 51.2 MB
    float* dinv   = (float*)(ws + o); o += (size_t)N * 4;       // deg -> dinv in place
    int*   cnt    = (int*)  (ws + o); o += (size_t)N * 4;
    int*   rowptr = (int*)  (ws + o); o += (size_t)N * 4;
    int*   cursor = (int*)  (ws + o); o += (size_t)N * 4;
    int nb = (N + 1023) / 1024;
    int*   blocksum = (int*)(ws + o); o += ((size_t)nb * 4 + 1023) / 1024 * 1024;
    int2*  sorted   = (int2*)(ws + o); o += (size_t)E * 8;      // 12.8 MB

    int gN = (N + 255) / 256;
    int gE = (E + 255) / 256;

    init_bufs<<<gN, 256, 0, stream>>>(dinv, cnt, N);
    count_deg<<<gE, 256, 0, stream>>>(coli, ew, dinv, cnt, E);
    compute_dinv<<<gN, 256, 0, stream>>>(dinv, N);
    scan_blocksum<<<nb, 256, 0, stream>>>(cnt, blocksum, N);
    scan_serial<<<1, 64, 0, stream>>>(blocksum, nb);
    scan_final<<<nb, 256, 0, stream>>>(cnt, blocksum, rowptr, cursor, N);
    scatter_edges<<<gE, 256, 0, stream>>>(rowi, coli, ew, dinv, cursor, sorted, E);
    gemm_xw<<<(N + 15) / 16, 256, 0, stream>>>(x, W, xw, N);
    aggregate<<<(N + 3) / 4, 256, 0, stream>>>(xw, dinv, rowptr, cnt, sorted, bias, prelu_a, out, N);
}

// Round 2
// 499.806 us; speedup vs baseline: 1.4719x; 1.4719x over previous
//
#include <hip/hip_runtime.h>
#include <hip/hip_bf16.h>

#define D 128  // D_IN == D_OUT == 128

typedef __attribute__((ext_vector_type(8))) short bf16x8;
typedef __attribute__((ext_vector_type(4))) float f32x4;

// fp32 -> bf16 with round-to-nearest-even (bit math, no NaN concerns here)
__device__ inline short f2bf(float f) {
    unsigned u = __float_as_uint(f);
    u = (u + 0x7FFFu + ((u >> 16) & 1u)) >> 16;
    return (short)u;
}

// ---------------- init: deg = 1.0 (self-loop), cnt = 0 ----------------
__global__ void init_bufs(float* __restrict__ deg, int* __restrict__ cnt, int N) {
    int i = blockIdx.x * 256 + threadIdx.x;
    if (i < N) { deg[i] = 1.0f; cnt[i] = 0; }
}

// ---------------- count pass: deg[col] += ew, cnt[col]++ ----------------
__global__ void count_deg(const int* __restrict__ col, const float* __restrict__ ew,
                          float* __restrict__ deg, int* __restrict__ cnt, int E) {
    int e = blockIdx.x * 256 + threadIdx.x;
    if (e >= E) return;
    int c = col[e];
    atomicAdd(&deg[c], ew[e]);
    atomicAdd(&cnt[c], 1);
}

// ---------------- dinv = rsqrt(deg) in place ----------------
__global__ void compute_dinv(float* __restrict__ deg, int N) {
    int i = blockIdx.x * 256 + threadIdx.x;
    if (i < N) { float d = deg[i]; deg[i] = (d > 0.f) ? rsqrtf(d) : 0.f; }
}

// ---------------- scan kernel 1: per-chunk (1024) sums ----------------
__global__ void scan_blocksum(const int* __restrict__ cnt, int* __restrict__ blocksum, int N) {
    __shared__ int sd[256];
    int tid = threadIdx.x;
    int base = blockIdx.x * 1024 + tid * 4;
    int s = 0;
    #pragma unroll
    for (int j = 0; j < 4; ++j) { int i = base + j; if (i < N) s += cnt[i]; }
    sd[tid] = s; __syncthreads();
    for (int off = 128; off > 0; off >>= 1) {
        if (tid < off) sd[tid] += sd[tid + off];
        __syncthreads();
    }
    if (tid == 0) blocksum[blockIdx.x] = sd[0];
}

// ---------------- scan kernel 2: serial exclusive scan of ~98 block sums ----------------
__global__ void scan_serial(int* __restrict__ blocksum, int nb) {
    if (threadIdx.x == 0 && blockIdx.x == 0) {
        int run = 0;
        for (int b = 0; b < nb; ++b) { int t = blocksum[b]; blocksum[b] = run; run += t; }
    }
}

// ---------------- scan kernel 3: intra-chunk exclusive scan -> rowptr, cursor ----------------
__global__ void scan_final(const int* __restrict__ cnt, const int* __restrict__ blocksum,
                           int* __restrict__ rowptr, int* __restrict__ cursor, int N) {
    __shared__ int sd[256];
    int tid = threadIdx.x;
    int base = blockIdx.x * 1024 + tid * 4;
    int v[4]; int tsum = 0;
    #pragma unroll
    for (int j = 0; j < 4; ++j) { int i = base + j; v[j] = (i < N) ? cnt[i] : 0; tsum += v[j]; }
    sd[tid] = tsum; __syncthreads();
    for (int off = 1; off < 256; off <<= 1) {
        int t = (tid >= off) ? sd[tid - off] : 0;
        __syncthreads();
        sd[tid] += t;
        __syncthreads();
    }
    int excl = sd[tid] - tsum + blocksum[blockIdx.x];
    #pragma unroll
    for (int j = 0; j < 4; ++j) {
        int i = base + j;
        if (i < N) { rowptr[i] = excl; cursor[i] = excl; }
        excl += v[j];
    }
}

// ---------------- scatter edges into CSR-by-target order ----------------
__global__ void scatter_edges(const int* __restrict__ rowi, const int* __restrict__ coli,
                              const float* __restrict__ ew, const float* __restrict__ dinv,
                              int* __restrict__ cursor, int2* __restrict__ sorted, int E) {
    int e = blockIdx.x * 256 + threadIdx.x;
    if (e >= E) return;
    int r = rowi[e], c = coli[e];
    float w = dinv[r] * ew[e];   // fold dinv[row]*ew into per-edge weight
    int pos = atomicAdd(&cursor[c], 1);
    sorted[pos] = make_int2(r, __float_as_int(w));
}

// ---------------- xw = x @ W via bf16 MFMA, fp32 accumulate ----------------
// Block = 256 (4 waves). Wave w computes rows [blk*64 + w*16, +16) x all 128 cols.
// W is pre-swizzled to B-fragment order in LDS: tile (kt,ct) holds 64 lanes x 8 bf16.
__global__ __launch_bounds__(256) void gemm_mfma(const float* __restrict__ x,
                                                 const float* __restrict__ W,
                                                 float* __restrict__ xw, int N) {
    __shared__ bf16x8 smW[2048];   // 4 kt * 8 ct * 64 lanes = 2048 frags, 32 KB
    int tid = threadIdx.x;

    // stage W (fp32 global, strided) -> bf16 B-frag layout in LDS
    for (int idx = tid; idx < 2048; idx += 256) {
        int tile = idx >> 6;           // kt*8 + ct
        int ln   = idx & 63;
        int kt   = tile >> 3;
        int ct   = tile & 7;
        int k0   = kt * 32 + (ln >> 4) * 8;
        int nn   = ct * 16 + (ln & 15);
        bf16x8 v;
        #pragma unroll
        for (int j = 0; j < 8; ++j) v[j] = f2bf(W[(k0 + j) * D + nn]);
        smW[idx] = v;
    }
    __syncthreads();

    int wid  = tid >> 6;
    int lane = tid & 63;
    int quad = lane >> 4;
    int m16  = lane & 15;
    int row0 = blockIdx.x * 64 + wid * 16;
    int row  = row0 + m16;             // A-frag row for this lane

    f32x4 acc[8];
    #pragma unroll
    for (int ct = 0; ct < 8; ++ct) acc[ct] = (f32x4){0.f, 0.f, 0.f, 0.f};

    #pragma unroll
    for (int kt = 0; kt < 4; ++kt) {
        bf16x8 a;
        if (row < N) {
            const float* xp = x + (size_t)row * D + kt * 32 + quad * 8;
            float4 u0 = *(const float4*)xp;
            float4 u1 = *(const float4*)(xp + 4);
            a[0] = f2bf(u0.x); a[1] = f2bf(u0.y); a[2] = f2bf(u0.z); a[3] = f2bf(u0.w);
            a[4] = f2bf(u1.x); a[5] = f2bf(u1.y); a[6] = f2bf(u1.z); a[7] = f2bf(u1.w);
        } else {
            #pragma unroll
            for (int j = 0; j < 8; ++j) a[j] = 0;
        }
        #pragma unroll
        for (int ct = 0; ct < 8; ++ct) {
            acc[ct] = __builtin_amdgcn_mfma_f32_16x16x32_bf16(
                a, smW[(kt * 8 + ct) * 64 + lane], acc[ct], 0, 0, 0);
        }
    }

    // C layout: col = lane&15, row = quad*4 + reg
    int rq = row0 + quad * 4;
    #pragma unroll
    for (int i = 0; i < 4; ++i) {
        int r = rq + i;
        if (r < N) {
            float* op = xw + (size_t)r * D + m16;
            #pragma unroll
            for (int ct = 0; ct < 8; ++ct) op[ct * 16] = acc[ct][i];
        }
    }
}

// ---------------- aggregation: one wave per node, cooperative edge loads ----------------
__global__ __launch_bounds__(256) void aggregate(const float* __restrict__ xw,
                                                 const float* __restrict__ dinv,
                                                 const int* __restrict__ rowptr,
                                                 const int* __restrict__ cnt,
                                                 const int2* __restrict__ sorted,
                                                 const float* __restrict__ bias,
                                                 const float* __restrict__ prelu_a,
                                                 float* __restrict__ out, int N) {
    int wid  = threadIdx.x >> 6;
    int lane = threadIdx.x & 63;
    int n = blockIdx.x * 4 + wid;
    if (n >= N) return;
    int d0 = lane * 2;
    float di = dinv[n];
    float2 xs = *(const float2*)(xw + (size_t)n * D + d0);
    float ax = di * xs.x;
    float ay = di * xs.y;
    int s = rowptr[n];
    int cn = cnt[n];
    for (int base = 0; base < cn; base += 64) {
        int rem = cn - base;
        int m = rem < 64 ? rem : 64;
        int2 er = make_int2(0, 0);
        if (lane < rem) er = sorted[s + base + lane];   // 64 edges per coalesced load
        int j = 0;
        for (; j + 4 <= m; j += 4) {
            int   r0 = __shfl(er.x, j + 0), r1 = __shfl(er.x, j + 1);
            int   r2 = __shfl(er.x, j + 2), r3 = __shfl(er.x, j + 3);
            float w0 = __int_as_float(__shfl(er.y, j + 0));
            float w1 = __int_as_float(__shfl(er.y, j + 1));
            float w2 = __int_as_float(__shfl(er.y, j + 2));
            float w3 = __int_as_float(__shfl(er.y, j + 3));
            float2 v0 = *(const float2*)(xw + (size_t)r0 * D + d0);
            float2 v1 = *(const float2*)(xw + (size_t)r1 * D + d0);
            float2 v2 = *(const float2*)(xw + (size_t)r2 * D + d0);
            float2 v3 = *(const float2*)(xw + (size_t)r3 * D + d0);
            ax = fmaf(w0, v0.x, ax); ay = fmaf(w0, v0.y, ay);
            ax = fmaf(w1, v1.x, ax); ay = fmaf(w1, v1.y, ay);
            ax = fmaf(w2, v2.x, ax); ay = fmaf(w2, v2.y, ay);
            ax = fmaf(w3, v3.x, ax); ay = fmaf(w3, v3.y, ay);
        }
        for (; j < m; ++j) {
            int   r = __shfl(er.x, j);
            float w = __int_as_float(__shfl(er.y, j));
            float2 v = *(const float2*)(xw + (size_t)r * D + d0);
            ax = fmaf(w, v.x, ax);
            ay = fmaf(w, v.y, ay);
        }
    }
    float a = prelu_a[0];
    float2 bv = *(const float2*)(bias + d0);
    float ox = fmaf(di, ax, bv.x);
    float oy = fmaf(di, ay, bv.y);
    ox = (ox >= 0.f) ? ox : a * ox;
    oy = (oy >= 0.f) ? oy : a * oy;
    *(float2*)(out + (size_t)n * D + d0) = make_float2(ox, oy);
}

extern "C" void kernel_launch(void* const* d_in, const int* in_sizes, int n_in,
                              void* d_out, int out_size, void* d_ws, size_t ws_size,
                              hipStream_t stream) {
    const float* x       = (const float*)d_in[0];
    const int*   ei      = (const int*)d_in[1];   // [2, E] int32
    const float* ew      = (const float*)d_in[2];
    const float* W       = (const float*)d_in[3];
    const float* bias    = (const float*)d_in[4];
    const float* prelu_a = (const float*)d_in[5];
    float* out = (float*)d_out;

    int N = in_sizes[0] / D;
    int E = in_sizes[2];
    const int* rowi = ei;       // source
    const int* coli = ei + E;   // target

    // workspace layout
    char* ws = (char*)d_ws;
    size_t o = 0;
    float* xw     = (float*)(ws + o); o += (size_t)N * D * 4;   // 51.2 MB
    float* dinv   = (float*)(ws + o); o += (size_t)N * 4;
    int*   cnt    = (int*)  (ws + o); o += (size_t)N * 4;
    int*   rowptr = (int*)  (ws + o); o += (size_t)N * 4;
    int*   cursor = (int*)  (ws + o); o += (size_t)N * 4;
    int nb = (N + 1023) / 1024;
    int*   blocksum = (int*)(ws + o); o += ((size_t)nb * 4 + 1023) / 1024 * 1024;
    int2*  sorted   = (int2*)(ws + o); o += (size_t)E * 8;      // 12.8 MB

    int gN = (N + 255) / 256;
    int gE = (E + 255) / 256;

    init_bufs<<<gN, 256, 0, stream>>>(dinv, cnt, N);
    count_deg<<<gE, 256, 0, stream>>>(coli, ew, dinv, cnt, E);
    compute_dinv<<<gN, 256, 0, stream>>>(dinv, N);
    scan_blocksum<<<nb, 256, 0, stream>>>(cnt, blocksum, N);
    scan_serial<<<1, 64, 0, stream>>>(blocksum, nb);
    scan_final<<<nb, 256, 0, stream>>>(cnt, blocksum, rowptr, cursor, N);
    scatter_edges<<<gE, 256, 0, stream>>>(rowi, coli, ew, dinv, cursor, sorted, E);
    gemm_mfma<<<(N + 63) / 64, 256, 0, stream>>>(x, W, xw, N);
    aggregate<<<(N + 3) / 4, 256, 0, stream>>>(xw, dinv, rowptr, cnt, sorted, bias, prelu_a, out, N);
}

// Round 3
// 371.899 us; speedup vs baseline: 1.9782x; 1.3439x over previous
//
#include <hip/hip_runtime.h>
#include <hip/hip_bf16.h>

#define D 128  // D_IN == D_OUT == 128
#define NREP 8 // degree-count replicas (≈ one per XCD)

typedef __attribute__((ext_vector_type(8))) short bf16x8;
typedef __attribute__((ext_vector_type(4))) float f32x4;

// fp32 -> bf16 round-to-nearest-even
__device__ inline unsigned short f2bf(float f) {
    unsigned u = __float_as_uint(f);
    u = (u + 0x7FFFu + ((u >> 16) & 1u)) >> 16;
    return (unsigned short)u;
}
__device__ inline float bf2f_lo(unsigned u) { return __uint_as_float(u << 16); }
__device__ inline float bf2f_hi(unsigned u) { return __uint_as_float(u & 0xFFFF0000u); }

// ---------------- zero the u64 replica buffer ----------------
__global__ void zero_u64(unsigned long long* __restrict__ p, int n) {
    int i = blockIdx.x * 256 + threadIdx.x;
    if (i < n) p[i] = 0ULL;
}

// ---------------- count pass: one u64 atomic per edge ----------------
// repl[rep*N + c] += (1<<48) | fixed32.32(ew)
__global__ void count_deg_packed(const int* __restrict__ col, const float* __restrict__ ew,
                                 unsigned long long* __restrict__ repl, int N, int E) {
    int e = blockIdx.x * 256 + threadIdx.x;
    if (e >= E) return;
    int c = col[e];
    unsigned long long fx = (unsigned long long)((double)ew[e] * 4294967296.0 + 0.5);
    unsigned long long v = (1ULL << 48) | fx;
    int rep = blockIdx.x & (NREP - 1);
    atomicAdd(&repl[(size_t)rep * N + c], v);
}

// ---------------- reduce replicas -> cnt, dinv ----------------
__global__ void reduce_deg(const unsigned long long* __restrict__ repl,
                           int* __restrict__ cnt, float* __restrict__ dinv, int N) {
    int i = blockIdx.x * 256 + threadIdx.x;
    if (i >= N) return;
    unsigned long long s = 0;
    #pragma unroll
    for (int r = 0; r < NREP; ++r) s += repl[(size_t)r * N + i];
    cnt[i] = (int)(s >> 48);
    double deg = 1.0 + (double)(s & 0xFFFFFFFFFFFFULL) * (1.0 / 4294967296.0);
    dinv[i] = (deg > 0.0) ? rsqrtf((float)deg) : 0.f;
}

// ---------------- scan kernel 1: per-chunk (1024) sums ----------------
__global__ void scan_blocksum(const int* __restrict__ cnt, int* __restrict__ blocksum, int N) {
    __shared__ int sd[256];
    int tid = threadIdx.x;
    int base = blockIdx.x * 1024 + tid * 4;
    int s = 0;
    #pragma unroll
    for (int j = 0; j < 4; ++j) { int i = base + j; if (i < N) s += cnt[i]; }
    sd[tid] = s; __syncthreads();
    for (int off = 128; off > 0; off >>= 1) {
        if (tid < off) sd[tid] += sd[tid + off];
        __syncthreads();
    }
    if (tid == 0) blocksum[blockIdx.x] = sd[0];
}

// ---------------- scan kernel 2: serial exclusive scan of block sums ----------------
__global__ void scan_serial(int* __restrict__ blocksum, int nb) {
    if (threadIdx.x == 0 && blockIdx.x == 0) {
        int run = 0;
        for (int b = 0; b < nb; ++b) { int t = blocksum[b]; blocksum[b] = run; run += t; }
    }
}

// ---------------- scan kernel 3: intra-chunk exclusive scan -> rowptr, cursor ----------------
__global__ void scan_final(const int* __restrict__ cnt, const int* __restrict__ blocksum,
                           int* __restrict__ rowptr, int* __restrict__ cursor, int N) {
    __shared__ int sd[256];
    int tid = threadIdx.x;
    int base = blockIdx.x * 1024 + tid * 4;
    int v[4]; int tsum = 0;
    #pragma unroll
    for (int j = 0; j < 4; ++j) { int i = base + j; v[j] = (i < N) ? cnt[i] : 0; tsum += v[j]; }
    sd[tid] = tsum; __syncthreads();
    for (int off = 1; off < 256; off <<= 1) {
        int t = (tid >= off) ? sd[tid - off] : 0;
        __syncthreads();
        sd[tid] += t;
        __syncthreads();
    }
    int excl = sd[tid] - tsum + blocksum[blockIdx.x];
    #pragma unroll
    for (int j = 0; j < 4; ++j) {
        int i = base + j;
        if (i < N) { rowptr[i] = excl; cursor[i] = excl; }
        excl += v[j];
    }
}

// ---------------- scatter edges into CSR-by-target order ----------------
__global__ void scatter_edges(const int* __restrict__ rowi, const int* __restrict__ coli,
                              const float* __restrict__ ew, const float* __restrict__ dinv,
                              int* __restrict__ cursor, int2* __restrict__ sorted, int E) {
    int e = blockIdx.x * 256 + threadIdx.x;
    if (e >= E) return;
    int r = rowi[e], c = coli[e];
    float w = dinv[r] * ew[e];   // fold dinv[row]*ew into per-edge weight
    int pos = atomicAdd(&cursor[c], 1);
    sorted[pos] = make_int2(r, __float_as_int(w));
}

// ---------------- xw = x @ W via bf16 MFMA, bf16 output ----------------
__global__ __launch_bounds__(256) void gemm_mfma(const float* __restrict__ x,
                                                 const float* __restrict__ W,
                                                 unsigned short* __restrict__ xw, int N) {
    __shared__ bf16x8 smW[2048];   // 4 kt * 8 ct * 64 lanes, 32 KB
    int tid = threadIdx.x;

    for (int idx = tid; idx < 2048; idx += 256) {
        int tile = idx >> 6;
        int ln   = idx & 63;
        int kt   = tile >> 3;
        int ct   = tile & 7;
        int k0   = kt * 32 + (ln >> 4) * 8;
        int nn   = ct * 16 + (ln & 15);
        bf16x8 v;
        #pragma unroll
        for (int j = 0; j < 8; ++j) v[j] = (short)f2bf(W[(k0 + j) * D + nn]);
        smW[idx] = v;
    }
    __syncthreads();

    int wid  = tid >> 6;
    int lane = tid & 63;
    int quad = lane >> 4;
    int m16  = lane & 15;
    int row0 = blockIdx.x * 64 + wid * 16;
    int row  = row0 + m16;

    f32x4 acc[8];
    #pragma unroll
    for (int ct = 0; ct < 8; ++ct) acc[ct] = (f32x4){0.f, 0.f, 0.f, 0.f};

    #pragma unroll
    for (int kt = 0; kt < 4; ++kt) {
        bf16x8 a;
        if (row < N) {
            const float* xp = x + (size_t)row * D + kt * 32 + quad * 8;
            float4 u0 = *(const float4*)xp;
            float4 u1 = *(const float4*)(xp + 4);
            a[0] = (short)f2bf(u0.x); a[1] = (short)f2bf(u0.y);
            a[2] = (short)f2bf(u0.z); a[3] = (short)f2bf(u0.w);
            a[4] = (short)f2bf(u1.x); a[5] = (short)f2bf(u1.y);
            a[6] = (short)f2bf(u1.z); a[7] = (short)f2bf(u1.w);
        } else {
            #pragma unroll
            for (int j = 0; j < 8; ++j) a[j] = 0;
        }
        #pragma unroll
        for (int ct = 0; ct < 8; ++ct) {
            acc[ct] = __builtin_amdgcn_mfma_f32_16x16x32_bf16(
                a, smW[(kt * 8 + ct) * 64 + lane], acc[ct], 0, 0, 0);
        }
    }

    // C layout: col = lane&15, row = quad*4 + reg
    int rq = row0 + quad * 4;
    #pragma unroll
    for (int i = 0; i < 4; ++i) {
        int r = rq + i;
        if (r < N) {
            unsigned short* op = xw + (size_t)r * D + m16;
            #pragma unroll
            for (int ct = 0; ct < 8; ++ct) op[ct * 16] = f2bf(acc[ct][i]);
        }
    }
}

// ---------------- aggregation: one wave per node, bf16 gathers ----------------
__global__ __launch_bounds__(256) void aggregate(const unsigned short* __restrict__ xw,
                                                 const float* __restrict__ dinv,
                                                 const int* __restrict__ rowptr,
                                                 const int* __restrict__ cnt,
                                                 const int2* __restrict__ sorted,
                                                 const float* __restrict__ bias,
                                                 const float* __restrict__ prelu_a,
                                                 float* __restrict__ out, int N) {
    int wid  = threadIdx.x >> 6;
    int lane = threadIdx.x & 63;
    int n = blockIdx.x * 4 + wid;
    if (n >= N) return;
    int d0 = lane * 2;
    float di = dinv[n];
    unsigned xs = *(const unsigned*)(xw + (size_t)n * D + d0);
    float ax = di * bf2f_lo(xs);
    float ay = di * bf2f_hi(xs);
    int s = rowptr[n];
    int cn = cnt[n];
    for (int base = 0; base < cn; base += 64) {
        int rem = cn - base;
        int m = rem < 64 ? rem : 64;
        int2 er = make_int2(0, 0);
        if (lane < rem) er = sorted[s + base + lane];
        int j = 0;
        for (; j + 4 <= m; j += 4) {
            int   r0 = __shfl(er.x, j + 0), r1 = __shfl(er.x, j + 1);
            int   r2 = __shfl(er.x, j + 2), r3 = __shfl(er.x, j + 3);
            float w0 = __int_as_float(__shfl(er.y, j + 0));
            float w1 = __int_as_float(__shfl(er.y, j + 1));
            float w2 = __int_as_float(__shfl(er.y, j + 2));
            float w3 = __int_as_float(__shfl(er.y, j + 3));
            unsigned v0 = *(const unsigned*)(xw + (size_t)r0 * D + d0);
            unsigned v1 = *(const unsigned*)(xw + (size_t)r1 * D + d0);
            unsigned v2 = *(const unsigned*)(xw + (size_t)r2 * D + d0);
            unsigned v3 = *(const unsigned*)(xw + (size_t)r3 * D + d0);
            ax = fmaf(w0, bf2f_lo(v0), ax); ay = fmaf(w0, bf2f_hi(v0), ay);
            ax = fmaf(w1, bf2f_lo(v1), ax); ay = fmaf(w1, bf2f_hi(v1), ay);
            ax = fmaf(w2, bf2f_lo(v2), ax); ay = fmaf(w2, bf2f_hi(v2), ay);
            ax = fmaf(w3, bf2f_lo(v3), ax); ay = fmaf(w3, bf2f_hi(v3), ay);
        }
        for (; j < m; ++j) {
            int   r = __shfl(er.x, j);
            float w = __int_as_float(__shfl(er.y, j));
            unsigned v = *(const unsigned*)(xw + (size_t)r * D + d0);
            ax = fmaf(w, bf2f_lo(v), ax);
            ay = fmaf(w, bf2f_hi(v), ay);
        }
    }
    float a = prelu_a[0];
    float2 bv = *(const float2*)(bias + d0);
    float ox = fmaf(di, ax, bv.x);
    float oy = fmaf(di, ay, bv.y);
    ox = (ox >= 0.f) ? ox : a * ox;
    oy = (oy >= 0.f) ? oy : a * oy;
    *(float2*)(out + (size_t)n * D + d0) = make_float2(ox, oy);
}

extern "C" void kernel_launch(void* const* d_in, const int* in_sizes, int n_in,
                              void* d_out, int out_size, void* d_ws, size_t ws_size,
                              hipStream_t stream) {
    const float* x       = (const float*)d_in[0];
    const int*   ei      = (const int*)d_in[1];   // [2, E] int32
    const float* ew      = (const float*)d_in[2];
    const float* W       = (const float*)d_in[3];
    const float* bias    = (const float*)d_in[4];
    const float* prelu_a = (const float*)d_in[5];
    float* out = (float*)d_out;

    int N = in_sizes[0] / D;
    int E = in_sizes[2];
    const int* rowi = ei;       // source
    const int* coli = ei + E;   // target

    // workspace layout (8B-aligned chunks first)
    char* ws = (char*)d_ws;
    size_t o = 0;
    unsigned long long* repl = (unsigned long long*)(ws + o); o += (size_t)NREP * N * 8; // 6.4 MB
    int2*  sorted = (int2*)(ws + o); o += (size_t)E * 8;                                 // 12.8 MB
    unsigned short* xw = (unsigned short*)(ws + o); o += (size_t)N * D * 2;              // 25.6 MB
    float* dinv   = (float*)(ws + o); o += (size_t)N * 4;
    int*   cnt    = (int*)  (ws + o); o += (size_t)N * 4;
    int*   rowptr = (int*)  (ws + o); o += (size_t)N * 4;
    int*   cursor = (int*)  (ws + o); o += (size_t)N * 4;
    int nb = (N + 1023) / 1024;
    int*   blocksum = (int*)(ws + o); o += ((size_t)nb * 4 + 1023) / 1024 * 1024;

    int gN = (N + 255) / 256;
    int gE = (E + 255) / 256;
    int nrep_elems = NREP * N;

    zero_u64<<<(nrep_elems + 255) / 256, 256, 0, stream>>>(repl, nrep_elems);
    count_deg_packed<<<gE, 256, 0, stream>>>(coli, ew, repl, N, E);
    reduce_deg<<<gN, 256, 0, stream>>>(repl, cnt, dinv, N);
    scan_blocksum<<<nb, 256, 0, stream>>>(cnt, blocksum, N);
    scan_serial<<<1, 64, 0, stream>>>(blocksum, nb);
    scan_final<<<nb, 256, 0, stream>>>(cnt, blocksum, rowptr, cursor, N);
    scatter_edges<<<gE, 256, 0, stream>>>(rowi, coli, ew, dinv, cursor, sorted, E);
    gemm_mfma<<<(N + 63) / 64, 256, 0, stream>>>(x, W, xw, N);
    aggregate<<<(N + 3) / 4, 256, 0, stream>>>(xw, dinv, rowptr, cnt, sorted, bias, prelu_a, out, N);
}

// Round 4
// 246.801 us; speedup vs baseline: 2.9809x; 1.5069x over previous
//
#include <hip/hip_runtime.h>
#include <hip/hip_bf16.h>

#define D 128        // D_IN == D_OUT == 128
#define NBMAX 512    // max buckets (N/256 <= 512 for N <= 131072)
#define CURPAD 16    // pad global cursors to one per 64B line

typedef __attribute__((ext_vector_type(8))) short bf16x8;
typedef __attribute__((ext_vector_type(4))) float f32x4;

// fp32 -> bf16 round-to-nearest-even
__device__ inline unsigned short f2bf(float f) {
    unsigned u = __float_as_uint(f);
    u = (u + 0x7FFFu + ((u >> 16) & 1u)) >> 16;
    return (unsigned short)u;
}
__device__ inline float bf2f_lo(unsigned u) { return __uint_as_float(u << 16); }
__device__ inline float bf2f_hi(unsigned u) { return __uint_as_float(u & 0xFFFF0000u); }

// ---------------- zero ints ----------------
__global__ void zero_int(int* __restrict__ p, int n) {
    int i = blockIdx.x * 256 + threadIdx.x;
    if (i < n) p[i] = 0;
}

// ---------------- bucket histogram: LDS hist, few global atomics ----------------
__global__ __launch_bounds__(256) void bucket_count(const int* __restrict__ coli,
                                                    int* __restrict__ bcount, int NB, int E) {
    __shared__ int hist[NBMAX];
    int tid = threadIdx.x;
    for (int i = tid; i < NBMAX; i += 256) hist[i] = 0;
    __syncthreads();
    int base = blockIdx.x * 4096;
    #pragma unroll
    for (int j = 0; j < 16; ++j) {
        int e = base + j * 256 + tid;
        if (e < E) atomicAdd(&hist[coli[e] >> 8], 1);
    }
    __syncthreads();
    for (int i = tid; i < NB; i += 256) {
        int c = hist[i];
        if (c) atomicAdd(&bcount[i * CURPAD], c);
    }
}

// ---------------- scan bucket counts -> bases + cursors ----------------
__global__ __launch_bounds__(512) void bucket_scan(const int* __restrict__ bcount,
                                                   int* __restrict__ bbase,
                                                   int* __restrict__ bcursor, int NB) {
    __shared__ int sd[512];
    int tid = threadIdx.x;
    int v = (tid < NB) ? bcount[tid * CURPAD] : 0;
    sd[tid] = v; __syncthreads();
    for (int off = 1; off < 512; off <<= 1) {
        int t = (tid >= off) ? sd[tid - off] : 0;
        __syncthreads(); sd[tid] += t; __syncthreads();
    }
    int excl = sd[tid] - v;
    if (tid < NB) { bbase[tid] = excl; bcursor[tid * CURPAD] = excl; }
    if (tid == NB - 1) bbase[NB] = excl + v;
}

// ---------------- phase 1: partition edges into buckets ----------------
// 1024 threads x 8 edges; per-edge rank via LDS atomics; one global atomic
// per (block,bucket) reserves the run.
__global__ __launch_bounds__(1024) void phase1(const int* __restrict__ rowi,
                                               const int* __restrict__ coli,
                                               const float* __restrict__ ew,
                                               int* __restrict__ bcursor,
                                               int2* __restrict__ tmp, int E) {
    __shared__ int hist[NBMAX];
    __shared__ int runbase[NBMAX];
    int tid = threadIdx.x;
    for (int i = tid; i < NBMAX; i += 1024) hist[i] = 0;
    __syncthreads();
    int base = blockIdx.x * 8192;
    int col[8], row[8], rank[8]; float w[8];
    #pragma unroll
    for (int j = 0; j < 8; ++j) {
        int e = base + j * 1024 + tid;
        if (e < E) {
            col[j] = coli[e]; row[j] = rowi[e]; w[j] = ew[e];
            rank[j] = atomicAdd(&hist[col[j] >> 8], 1);
        }
    }
    __syncthreads();
    for (int i = tid; i < NBMAX; i += 1024) {
        int c = hist[i];
        runbase[i] = c ? atomicAdd(&bcursor[i * CURPAD], c) : 0;
    }
    __syncthreads();
    #pragma unroll
    for (int j = 0; j < 8; ++j) {
        int e = base + j * 1024 + tid;
        if (e < E) {
            int b = col[j] >> 8;
            int pos = runbase[b] + rank[j];
            tmp[pos] = make_int2(((col[j] & 255) << 24) | row[j], __float_as_int(w[j]));
        }
    }
}

// ---------------- phase 2: per-bucket counting sort (all in LDS) ----------------
// One block per bucket (256 nodes). Produces rowptr, cnt, dinv, and final CSR.
__global__ __launch_bounds__(256) void phase2(const int2* __restrict__ tmp,
                                              const int* __restrict__ bbase,
                                              int* __restrict__ rowptr, int* __restrict__ cnt,
                                              float* __restrict__ dinv,
                                              int2* __restrict__ sorted, int N) {
    __shared__ unsigned int cnt_s[256];
    __shared__ unsigned long long deg_s[256];
    __shared__ int scan_s[256];
    __shared__ int cur[256];
    int tid = threadIdx.x;
    cnt_s[tid] = 0; deg_s[tid] = 0;
    __syncthreads();
    int start = bbase[blockIdx.x];
    int end   = bbase[blockIdx.x + 1];
    for (int e = start + tid; e < end; e += 256) {
        int2 v = tmp[e];
        unsigned coff = ((unsigned)v.x) >> 24;
        atomicAdd(&cnt_s[coff], 1u);
        unsigned long long fx =
            (unsigned long long)(__int_as_float(v.y) * 1048576.0f + 0.5f);
        atomicAdd(&deg_s[coff], fx);
    }
    __syncthreads();
    int v0 = (int)cnt_s[tid];
    scan_s[tid] = v0; __syncthreads();
    for (int off = 1; off < 256; off <<= 1) {
        int t = (tid >= off) ? scan_s[tid - off] : 0;
        __syncthreads(); scan_s[tid] += t; __syncthreads();
    }
    int excl = scan_s[tid] - v0;
    int node = blockIdx.x * 256 + tid;
    if (node < N) {
        rowptr[node] = start + excl;
        cnt[node] = v0;
        float deg = 1.0f + (float)((double)deg_s[tid] * (1.0 / 1048576.0));
        dinv[node] = rsqrtf(deg);   // deg >= 1 (self-loop)
    }
    cur[tid] = start + excl;
    __syncthreads();
    for (int e = start + tid; e < end; e += 256) {
        int2 v = tmp[e];
        unsigned coff = ((unsigned)v.x) >> 24;
        int pos = atomicAdd(&cur[coff], 1);
        sorted[pos] = make_int2(v.x & 0xFFFFFF, v.y);   // (row, ew)
    }
}

// ---------------- xw = x @ W via bf16 MFMA, bf16 output ----------------
__global__ __launch_bounds__(256) void gemm_mfma(const float* __restrict__ x,
                                                 const float* __restrict__ W,
                                                 unsigned short* __restrict__ xw, int N) {
    __shared__ bf16x8 smW[2048];   // 4 kt * 8 ct * 64 lanes, 32 KB
    int tid = threadIdx.x;

    for (int idx = tid; idx < 2048; idx += 256) {
        int tile = idx >> 6;
        int ln   = idx & 63;
        int kt   = tile >> 3;
        int ct   = tile & 7;
        int k0   = kt * 32 + (ln >> 4) * 8;
        int nn   = ct * 16 + (ln & 15);
        bf16x8 v;
        #pragma unroll
        for (int j = 0; j < 8; ++j) v[j] = (short)f2bf(W[(k0 + j) * D + nn]);
        smW[idx] = v;
    }
    __syncthreads();

    int wid  = tid >> 6;
    int lane = tid & 63;
    int quad = lane >> 4;
    int m16  = lane & 15;
    int row0 = blockIdx.x * 64 + wid * 16;
    int row  = row0 + m16;

    f32x4 acc[8];
    #pragma unroll
    for (int ct = 0; ct < 8; ++ct) acc[ct] = (f32x4){0.f, 0.f, 0.f, 0.f};

    #pragma unroll
    for (int kt = 0; kt < 4; ++kt) {
        bf16x8 a;
        if (row < N) {
            const float* xp = x + (size_t)row * D + kt * 32 + quad * 8;
            float4 u0 = *(const float4*)xp;
            float4 u1 = *(const float4*)(xp + 4);
            a[0] = (short)f2bf(u0.x); a[1] = (short)f2bf(u0.y);
            a[2] = (short)f2bf(u0.z); a[3] = (short)f2bf(u0.w);
            a[4] = (short)f2bf(u1.x); a[5] = (short)f2bf(u1.y);
            a[6] = (short)f2bf(u1.z); a[7] = (short)f2bf(u1.w);
        } else {
            #pragma unroll
            for (int j = 0; j < 8; ++j) a[j] = 0;
        }
        #pragma unroll
        for (int ct = 0; ct < 8; ++ct) {
            acc[ct] = __builtin_amdgcn_mfma_f32_16x16x32_bf16(
                a, smW[(kt * 8 + ct) * 64 + lane], acc[ct], 0, 0, 0);
        }
    }

    int rq = row0 + quad * 4;
    #pragma unroll
    for (int i = 0; i < 4; ++i) {
        int r = rq + i;
        if (r < N) {
            unsigned short* op = xw + (size_t)r * D + m16;
            #pragma unroll
            for (int ct = 0; ct < 8; ++ct) op[ct * 16] = f2bf(acc[ct][i]);
        }
    }
}

// ---------------- aggregation: one wave per node, bf16 gathers ----------------
__global__ __launch_bounds__(256) void aggregate(const unsigned short* __restrict__ xw,
                                                 const float* __restrict__ dinv,
                                                 const int* __restrict__ rowptr,
                                                 const int* __restrict__ cnt,
                                                 const int2* __restrict__ sorted,
                                                 const float* __restrict__ bias,
                                                 const float* __restrict__ prelu_a,
                                                 float* __restrict__ out, int N) {
    int wid  = threadIdx.x >> 6;
    int lane = threadIdx.x & 63;
    int n = blockIdx.x * 4 + wid;
    if (n >= N) return;
    int d0 = lane * 2;
    float di = dinv[n];
    unsigned xs = *(const unsigned*)(xw + (size_t)n * D + d0);
    float ax = di * bf2f_lo(xs);
    float ay = di * bf2f_hi(xs);
    int s = rowptr[n];
    int cn = cnt[n];
    for (int base = 0; base < cn; base += 64) {
        int rem = cn - base;
        int m = rem < 64 ? rem : 64;
        int rsrc = 0; float wv = 0.f;
        if (lane < rem) {
            int2 er = sorted[s + base + lane];
            rsrc = er.x;
            wv = dinv[er.x] * __int_as_float(er.y);   // fold dinv[row] here
        }
        int j = 0;
        for (; j + 4 <= m; j += 4) {
            int   r0 = __shfl(rsrc, j + 0), r1 = __shfl(rsrc, j + 1);
            int   r2 = __shfl(rsrc, j + 2), r3 = __shfl(rsrc, j + 3);
            float w0 = __shfl(wv, j + 0), w1 = __shfl(wv, j + 1);
            float w2 = __shfl(wv, j + 2), w3 = __shfl(wv, j + 3);
            unsigned v0 = *(const unsigned*)(xw + (size_t)r0 * D + d0);
            unsigned v1 = *(const unsigned*)(xw + (size_t)r1 * D + d0);
            unsigned v2 = *(const unsigned*)(xw + (size_t)r2 * D + d0);
            unsigned v3 = *(const unsigned*)(xw + (size_t)r3 * D + d0);
            ax = fmaf(w0, bf2f_lo(v0), ax); ay = fmaf(w0, bf2f_hi(v0), ay);
            ax = fmaf(w1, bf2f_lo(v1), ax); ay = fmaf(w1, bf2f_hi(v1), ay);
            ax = fmaf(w2, bf2f_lo(v2), ax); ay = fmaf(w2, bf2f_hi(v2), ay);
            ax = fmaf(w3, bf2f_lo(v3), ax); ay = fmaf(w3, bf2f_hi(v3), ay);
        }
        for (; j < m; ++j) {
            int   r = __shfl(rsrc, j);
            float w = __shfl(wv, j);
            unsigned v = *(const unsigned*)(xw + (size_t)r * D + d0);
            ax = fmaf(w, bf2f_lo(v), ax);
            ay = fmaf(w, bf2f_hi(v), ay);
        }
    }
    float a = prelu_a[0];
    float2 bv = *(const float2*)(bias + d0);
    float ox = fmaf(di, ax, bv.x);
    float oy = fmaf(di, ay, bv.y);
    ox = (ox >= 0.f) ? ox : a * ox;
    oy = (oy >= 0.f) ? oy : a * oy;
    *(float2*)(out + (size_t)n * D + d0) = make_float2(ox, oy);
}

extern "C" void kernel_launch(void* const* d_in, const int* in_sizes, int n_in,
                              void* d_out, int out_size, void* d_ws, size_t ws_size,
                              hipStream_t stream) {
    const float* x       = (const float*)d_in[0];
    const int*   ei      = (const int*)d_in[1];   // [2, E] int32
    const float* ew      = (const float*)d_in[2];
    const float* W       = (const float*)d_in[3];
    const float* bias    = (const float*)d_in[4];
    const float* prelu_a = (const float*)d_in[5];
    float* out = (float*)d_out;

    int N = in_sizes[0] / D;
    int E = in_sizes[2];
    const int* rowi = ei;       // source
    const int* coli = ei + E;   // target
    int NB = (N + 255) >> 8;    // buckets of 256 nodes

    // workspace layout
    char* ws = (char*)d_ws;
    size_t o = 0;
    int2*  tmp    = (int2*)(ws + o); o += (size_t)E * 8;                    // 12.8 MB
    int2*  sorted = (int2*)(ws + o); o += (size_t)E * 8;                    // 12.8 MB
    unsigned short* xw = (unsigned short*)(ws + o); o += (size_t)N * D * 2; // 25.6 MB
    int* bcount  = (int*)(ws + o); o += (size_t)NB * CURPAD * 4;
    int* bcursor = (int*)(ws + o); o += (size_t)NB * CURPAD * 4;
    int* bbase   = (int*)(ws + o); o += ((size_t)NB + 1) * 4;
    o = (o + 255) & ~(size_t)255;
    int* rowptr  = (int*)(ws + o); o += (size_t)N * 4;
    int* cnt     = (int*)(ws + o); o += (size_t)N * 4;
    float* dinv  = (float*)(ws + o); o += (size_t)N * 4;

    zero_int<<<(NB * CURPAD + 255) / 256, 256, 0, stream>>>(bcount, NB * CURPAD);
    bucket_count<<<(E + 4095) / 4096, 256, 0, stream>>>(coli, bcount, NB, E);
    bucket_scan<<<1, 512, 0, stream>>>(bcount, bbase, bcursor, NB);
    phase1<<<(E + 8191) / 8192, 1024, 0, stream>>>(rowi, coli, ew, bcursor, tmp, E);
    phase2<<<NB, 256, 0, stream>>>(tmp, bbase, rowptr, cnt, dinv, sorted, N);
    gemm_mfma<<<(N + 63) / 64, 256, 0, stream>>>(x, W, xw, N);
    aggregate<<<(N + 3) / 4, 256, 0, stream>>>(xw, dinv, rowptr, cnt, sorted, bias, prelu_a, out, N);
}